// Round 4
// baseline (463.617 us; speedup 1.0000x reference)
//
#include <hip/hip_runtime.h>

// KAN layer: out = x @ Wb^T + einsum(basis(x), S)
// One bf16 MFMA GEMM: out = A_aug (8192x9216) @ W_aug^T (1024x9216)
// R1: build kernels — compile-time knots, 8 feat/thread, 16B stores.
// R2: granule swizzle NEUTRAL (conflicts structural to b128 reads).
// R3: XCD grid (x=bm): FETCH 599->170MB. split-K dropped (atomic+memset cost).
// R4: BK=64 flat REGRESSED (128B stride = 16-way bank conflicts). Reverted.
// R5: two BK=32 panels per barrier: 242->188us, MfmaUtil 36%.
// R6: four BK=32 panels per barrier: ~180us GEMM, MfmaUtil 38% == m97 ceiling.
// R7: T2+T3+T4+T5: BM=256 BN=128 BK=64, 8 waves, 3-buf LDS, vmcnt(6), XOR
//     swizzle. 154us, BANK_CONFLICT 1.9e7->0, MfmaUtil 43%.
// R8: 2x16-MFMA phases, 3 barriers/tile: 143us, MfmaUtil 47%.
// R9: 1 barrier/tile (wave skew): 135us, MfmaUtil 52%. Model CLOSED: LDS
//     traffic incl. global_load_lds WRITES = 176KB/tile -> ~2070cy roofline;
//     measured 2248cy = 93%. Schedule done; must cut LDS bytes.
// R10: A direct global->VGPR (fragment rows are wave-private; no swizzle
//     needed). LDS = B only: 3 x 16KB, traffic 80KB/tile (not binding).
//     New bound = MFMA 1241cy/tile -> 74.5us ideal. A-frags double-buffered
//     in named reg sets (rule #20); per-body VMEM = 8 A-loads(t+1) +
//     2 B-stages(t+2) -> order-robust top-of-tile vmcnt(10) (vmcnt(0) at t=0,
//     vmcnt(8) at last tile); compiler waitcnt covers A-reg deps.
//     Predict: gemm 135->85-100us, MfmaUtil 62-75, LDS 48KB, conflicts 0.
//     Watch: if ~110us + MfmaUtil ~55 -> TA-request-bound on 64B segments.

#define BATCH 8192
#define IN_F  1024
#define OUT_F 1024
#define NC    9                 // 1 (base) + GRID + K (spline coeffs)
#define KAUG  (IN_F * NC)       // 9216

typedef float  f32x4  __attribute__((ext_vector_type(4)));
typedef __bf16 bf16x8 __attribute__((ext_vector_type(8)));
typedef unsigned short u16;
typedef u16 u16x8 __attribute__((ext_vector_type(8)));

__device__ __forceinline__ u16 f2bf(float f) {
  unsigned int u = __builtin_bit_cast(unsigned int, f);
  u += 0x7FFFu + ((u >> 16) & 1u);          // round-to-nearest-even
  return (u16)(u >> 16);
}

// knot j (j=0..11): value (j-3)*0.4 - 1, fp32 exactly like the reference
#define KT(j) ((float)((j) - 3) * 0.4f - 1.0f)

__device__ __forceinline__ void bspline8(float x, float bas[11]) {
#pragma unroll
  for (int j = 0; j < 11; ++j)
    bas[j] = (x >= KT(j) && x < KT(j + 1)) ? 1.0f : 0.0f;
#pragma unroll
  for (int p = 1; p <= 3; ++p) {
#pragma unroll
    for (int j = 0; j < 11 - p; ++j) {
      bas[j] = (x - KT(j)) * (1.0f / (KT(j + p) - KT(j))) * bas[j]
             + (KT(j + p + 1) - x) * (1.0f / (KT(j + p + 1) - KT(j + 1))) * bas[j + 1];
    }
  }
}

// -------- merged build: A_aug (idx < BATCH*128) and W_aug (rest) -------------
__global__ __launch_bounds__(256) void build_AW(const float* __restrict__ X,
                                                const float* __restrict__ BW,
                                                const float* __restrict__ SW,
                                                u16* __restrict__ Aa,
                                                u16* __restrict__ Wa) {
  const int idx = blockIdx.x * 256 + threadIdx.x;
  if (idx < BATCH * 128) {                       // ---- A path ----
    const int b  = idx >> 7;
    const int i0 = (idx & 127) << 3;
    const float4* xp = (const float4*)(X + (size_t)b * IN_F + i0);
    float4 xa = xp[0], xb = xp[1];
    float xs[8] = {xa.x, xa.y, xa.z, xa.w, xb.x, xb.y, xb.z, xb.w};
    u16x8 out[9];
#pragma unroll
    for (int e = 0; e < 8; ++e) {
      const float x = xs[e];
      out[0][e] = f2bf(x);
      float bas[11];
      bspline8(x, bas);
#pragma unroll
      for (int c = 0; c < 8; ++c) out[c + 1][e] = f2bf(bas[c]);
    }
    u16* row = Aa + (size_t)b * KAUG + i0;
#pragma unroll
    for (int c = 0; c < 9; ++c) *(u16x8*)(row + c * IN_F) = out[c];
  } else {                                       // ---- W path ----
    const int wdx = idx - BATCH * 128;
    const int o  = wdx >> 7;
    const int i0 = (wdx & 127) << 3;
    u16x8 out[9];
    const float4* bp = (const float4*)(BW + (size_t)o * IN_F + i0);
    float4 b0 = bp[0], b1 = bp[1];
    float bs[8] = {b0.x, b0.y, b0.z, b0.w, b1.x, b1.y, b1.z, b1.w};
#pragma unroll
    for (int e = 0; e < 8; ++e) out[0][e] = f2bf(bs[e]);
    const float4* sp = (const float4*)(SW + ((size_t)o * IN_F + i0) * 8);
#pragma unroll
    for (int e = 0; e < 8; ++e) {
      float4 s0 = sp[e * 2], s1 = sp[e * 2 + 1];
      out[1][e] = f2bf(s0.x);
      out[2][e] = f2bf(s0.y);
      out[3][e] = f2bf(s0.z);
      out[4][e] = f2bf(s0.w);
      out[5][e] = f2bf(s1.x);
      out[6][e] = f2bf(s1.y);
      out[7][e] = f2bf(s1.z);
      out[8][e] = f2bf(s1.w);
    }
    u16* row = Wa + (size_t)o * KAUG + i0;
#pragma unroll
    for (int c = 0; c < 9; ++c) *(u16x8*)(row + c * IN_F) = out[c];
  }
}

// ---- stage 3: bf16 MFMA GEMM, C = A * B^T, A-in-registers ------------------
#define BM 256
#define BN 128
#define BK 64
#define NT (KAUG / BK)          // 144 K-tiles

__device__ __forceinline__ void async16(const u16* g, u16* l) {
  __builtin_amdgcn_global_load_lds(
      (const __attribute__((address_space(1))) u16*)g,
      (__attribute__((address_space(3))) u16*)l,
      16, 0, 0);
}

__global__ __launch_bounds__(512, 2) void gemm_bt(
    const u16* __restrict__ A,   // M x K bf16
    const u16* __restrict__ B,   // N x K bf16 (i.e. B^T operand)
    float* __restrict__ C) {     // M x N fp32
  constexpr int N = OUT_F, K = KAUG;
  // B only in LDS: 3 buffers x [128 rows][64 k] bf16 = 3 x 16 KiB
  __shared__ __align__(16) u16 smB[3][8192];

  const int tid = threadIdx.x;

  // XCD-contiguous tiles: 256 wgs / 8 XCDs; XCD x owns bm in [x*4, x*4+4).
  const int bid = blockIdx.x;
  const int wg  = (bid & 7) * 32 + (bid >> 3);   // bijective (256 = 8*32)
  const int bm  = wg >> 3;                       // 0..31
  const int bn  = wg & 7;                        // 0..7

  const int lane = tid & 63;
  const int wid  = tid >> 6;                     // 8 waves
  const int wm   = wid >> 1;                     // 0..3  (64-row strip)
  const int wn   = wid & 1;                      // 0..1  (64-col strip)
  const int fr   = lane & 15;
  const int hi   = lane >> 4;

  // B fragment LDS offsets (XOR-swizzled, u16 units)
  const int ak0 = ((hi      ^ (fr & 7)) << 3);
  const int ak1 = (((4 | hi) ^ (fr & 7)) << 3);
  int brow[4];
#pragma unroll
  for (int n = 0; n < 4; ++n) brow[n] = (wn * 64 + n * 16 + fr) * 64;

  // B staging: thread t covers rows tid>>3 and 64+(tid>>3), granule tid&7
  // (linear LDS dest; inverse swizzle on the GLOBAL source granule).
  const int trow = tid >> 3;
  const int gsrc = (tid & 7) ^ (trow & 7);
  const u16* Bsrc = B + (size_t)(bn * BN + trow) * K + gsrc * 8;

  // A fragment base: per-lane row (wave-private), granule hi. No swizzle.
  const u16* Abase = A + (size_t)(bm * BM + wm * 64 + fr) * K + hi * 8;

  // prologue: A(0) frags -> regs, then stage B(0), B(1)
  bf16x8 aA[4][2], aB[4][2];
#pragma unroll
  for (int m = 0; m < 4; ++m)
#pragma unroll
    for (int kc = 0; kc < 2; ++kc)
      aA[m][kc] = *(const bf16x8*)(Abase + (size_t)m * 16 * K + kc * 32);
#pragma unroll
  for (int tt = 0; tt < 2; ++tt) {
    u16* dB = &smB[tt][tid * 8];
    async16(Bsrc + tt * BK, dB);
    async16(Bsrc + (size_t)64 * K + tt * BK, dB + 4096);
  }

  f32x4 acc[4][4] = {};

  // Per tile body t: issues exactly 10 VMEM ops (8 A-frag loads for t+1,
  // 2 B stages for t+2). Top-of-tile vmcnt(10) therefore drains B(t)
  // (issued in body t-2) regardless of intra-body issue order; the
  // compiler's own waitcnt covers the A-register dependencies.
  auto tile = [&](int t, bf16x8 (&cur)[4][2], bf16x8 (&nxt)[4][2]) {
    const int cb = t % 3;
    const int nb = (t + 2) % 3;
    const u16* sB = &smB[cb][0];
    u16* dB = &smB[nb][tid * 8];

    if (t == 0)           asm volatile("s_waitcnt vmcnt(0)"  ::: "memory");
    else if (t == NT - 1) asm volatile("s_waitcnt vmcnt(8)"  ::: "memory");
    else                  asm volatile("s_waitcnt vmcnt(10)" ::: "memory");
    __builtin_amdgcn_s_barrier();                // publish B(t); reuse guard
    __builtin_amdgcn_sched_barrier(0);           // nothing crosses tile top

    bf16x8 bf[4];
    // ---- kc0: B frags + A(t+1) issue + 16 MFMA ----
#pragma unroll
    for (int n = 0; n < 4; ++n) bf[n] = *(const bf16x8*)(sB + brow[n] + ak0);
    if (t + 1 < NT) {
#pragma unroll
      for (int m = 0; m < 4; ++m)
#pragma unroll
        for (int kc = 0; kc < 2; ++kc)
          nxt[m][kc] = *(const bf16x8*)(Abase + (size_t)m * 16 * K + kc * 32
                                        + (size_t)(t + 1) * BK);
    }
    __builtin_amdgcn_s_setprio(1);
#pragma unroll
    for (int m = 0; m < 4; ++m)
#pragma unroll
      for (int n = 0; n < 4; ++n)
        acc[m][n] = __builtin_amdgcn_mfma_f32_16x16x32_bf16(cur[m][0], bf[n], acc[m][n], 0, 0, 0);
    __builtin_amdgcn_s_setprio(0);
    // ---- kc1: B frags + B(t+2) stage + 16 MFMA ----
#pragma unroll
    for (int n = 0; n < 4; ++n) bf[n] = *(const bf16x8*)(sB + brow[n] + ak1);
    if (t + 2 < NT) {
      async16(Bsrc + (size_t)(t + 2) * BK, dB);
      async16(Bsrc + (size_t)64 * K + (size_t)(t + 2) * BK, dB + 4096);
    }
    __builtin_amdgcn_s_setprio(1);
#pragma unroll
    for (int m = 0; m < 4; ++m)
#pragma unroll
      for (int n = 0; n < 4; ++n)
        acc[m][n] = __builtin_amdgcn_mfma_f32_16x16x32_bf16(cur[m][1], bf[n], acc[m][n], 0, 0, 0);
    __builtin_amdgcn_s_setprio(0);
  };

  for (int t = 0; t < NT; t += 2) {              // NT even; named reg sets
    tile(t,     aA, aB);
    tile(t + 1, aB, aA);
  }

  // C/D layout (16x16): col = lane&15, row = (lane>>4)*4 + reg
  const int r0 = bm * BM + wm * 64 + hi * 4;
  const int c0 = bn * BN + wn * 64 + fr;
#pragma unroll
  for (int i = 0; i < 4; ++i)
#pragma unroll
    for (int j = 0; j < 4; ++j) {
      float* cp = C + (size_t)(r0 + i * 16) * N + (c0 + j * 16);
#pragma unroll
      for (int r = 0; r < 4; ++r) cp[(size_t)r * N] = acc[i][j][r];
    }
}

extern "C" void kernel_launch(void* const* d_in, const int* in_sizes, int n_in,
                              void* d_out, int out_size, void* d_ws, size_t ws_size,
                              hipStream_t stream) {
  const float* x  = (const float*)d_in[0];   // (8192, 1024)
  const float* bw = (const float*)d_in[1];   // (1024, 1024)
  const float* sw = (const float*)d_in[2];   // (1024, 1024, 8)
  // d_in[3] = grid (1024, 12): compile-time uniform knots; unused.
  float* out = (float*)d_out;                // (8192, 1024)

  u16* Aaug = (u16*)d_ws;                    // 151 MB
  u16* Waug = Aaug + (size_t)BATCH * KAUG;   // 19 MB

  build_AW<<<dim3((BATCH + OUT_F) * 128 / 256), 256, 0, stream>>>(x, bw, sw, Aaug, Waug);
  gemm_bt<<<dim3(BATCH / BM * (OUT_F / BN)), 512, 0, stream>>>(Aaug, Waug, out);
}

// Round 5
// 273.088 us; speedup vs baseline: 1.6977x; 1.6977x over previous
//
#include <hip/hip_runtime.h>

// KAN layer: out = x @ Wb^T + einsum(basis(x), S)
// One bf16 MFMA GEMM: out = A_aug (8192x9216) @ W_aug^T (1024x9216)
// R1-R6: build + m97-style GEMM ladder -> 180us gemm, MfmaUtil 38%.
// R7: T2+T3+T4+T5: BM=256 BN=128 BK=64, 8 waves, 3-buf LDS, vmcnt(6), XOR
//     swizzle. 154us, BANK_CONFLICT 1.9e7->0, MfmaUtil 43%.
// R8: 2x16-MFMA phases, 3 barriers/tile: 143us, MfmaUtil 47%.
// R9: 1 barrier/tile (wave skew): 135us, MfmaUtil 52%. Model CLOSED: LDS
//     traffic incl. global_load_lds WRITES = 176KB/tile -> ~2070cy roofline;
//     measured 2248cy = 93%. GEMM is ~done at this tiling.
// R10: A-direct-to-VGPR REGRESSED 339us: compiler kept VGPR=92 (needs ~150),
//     demoted A-frag double buffer -> MFMA serialized on global latency
//     (MfmaUtil 18.5, VALU 7, HBM 6.8). REVERTED to R9 gemm.
// R11: build_AW VALU cut: uniform knots => closed-form cubic basis.
//     cell c = floor((x+2.2f)*2.5f), u local; 4 nonzero values are the
//     standard uniform cubic B-spline polys {(1-u)^3, 3u^3-6u^2+4,
//     -3u^3+3u^2+3u+1, u^3}/6 scattered to slots c-3..c (r=j-c+3 in [0,3]
//     auto-rejects out-of-domain c). ~85 VALU/elem vs ~200 (Cox-de Boor).
//     Rest-of-iteration has been 125-136us for 5 rounds (> gemm roofline 38us
//     for build memory). Predict: gemm ~135us unchanged; total 271 -> 215-235
//     if build was VALU-bound; if total >=260, rest is memory/overhead floor.

#define BATCH 8192
#define IN_F  1024
#define OUT_F 1024
#define NC    9                 // 1 (base) + GRID + K (spline coeffs)
#define KAUG  (IN_F * NC)       // 9216

typedef float  f32x4  __attribute__((ext_vector_type(4)));
typedef __bf16 bf16x8 __attribute__((ext_vector_type(8)));
typedef unsigned short u16;
typedef u16 u16x8 __attribute__((ext_vector_type(8)));

__device__ __forceinline__ u16 f2bf(float f) {
  unsigned int u = __builtin_bit_cast(unsigned int, f);
  u += 0x7FFFu + ((u >> 16) & 1u);          // round-to-nearest-even
  return (u16)(u >> 16);
}

// knots are uniform: KT(j) = (j-3)*0.4 - 1, j=0..11; KT(0) == -(2.2f) exactly.
// Closed-form degree-3 basis: x in cell c (= [KT(c),KT(c+1))), u = local coord;
// nonzero basis indices j = c-3..c with the standard uniform cubic polys.
__device__ __forceinline__ void bspline8(float x, float bas[8]) {
  const float t  = (x + 2.2f) * 2.5f;       // (x - KT(0)) / h
  const float cf = floorf(t);
  const int   c  = (int)cf;
  const float u  = t - cf;                  // [0,1)
  const float u2 = u * u, u3 = u2 * u;
  const float um = 1.0f - u;
  const float b0 = um * um * um * (1.0f / 6.0f);
  const float b1 = (3.0f * u3 - 6.0f * u2 + 4.0f) * (1.0f / 6.0f);
  const float b2 = (-3.0f * u3 + 3.0f * u2 + 3.0f * u + 1.0f) * (1.0f / 6.0f);
  const float b3 = u3 * (1.0f / 6.0f);
#pragma unroll
  for (int j = 0; j < 8; ++j) {
    const int r = j - c + 3;                // which of b0..b3 (static per j: cndmask chain)
    bas[j] = (r == 0) ? b0 : (r == 1) ? b1 : (r == 2) ? b2 : (r == 3) ? b3 : 0.0f;
  }
}

// -------- merged build: A_aug (idx < BATCH*128) and W_aug (rest) -------------
__global__ __launch_bounds__(256) void build_AW(const float* __restrict__ X,
                                                const float* __restrict__ BW,
                                                const float* __restrict__ SW,
                                                u16* __restrict__ Aa,
                                                u16* __restrict__ Wa) {
  const int idx = blockIdx.x * 256 + threadIdx.x;
  if (idx < BATCH * 128) {                       // ---- A path ----
    const int b  = idx >> 7;
    const int i0 = (idx & 127) << 3;
    const float4* xp = (const float4*)(X + (size_t)b * IN_F + i0);
    float4 xa = xp[0], xb = xp[1];
    float xs[8] = {xa.x, xa.y, xa.z, xa.w, xb.x, xb.y, xb.z, xb.w};
    u16x8 out[9];
#pragma unroll
    for (int e = 0; e < 8; ++e) {
      const float x = xs[e];
      out[0][e] = f2bf(x);
      float bas[8];
      bspline8(x, bas);
#pragma unroll
      for (int c = 0; c < 8; ++c) out[c + 1][e] = f2bf(bas[c]);
    }
    u16* row = Aa + (size_t)b * KAUG + i0;
#pragma unroll
    for (int c = 0; c < 9; ++c) *(u16x8*)(row + c * IN_F) = out[c];
  } else {                                       // ---- W path ----
    const int wdx = idx - BATCH * 128;
    const int o  = wdx >> 7;
    const int i0 = (wdx & 127) << 3;
    u16x8 out[9];
    const float4* bp = (const float4*)(BW + (size_t)o * IN_F + i0);
    float4 b0 = bp[0], b1 = bp[1];
    float bs[8] = {b0.x, b0.y, b0.z, b0.w, b1.x, b1.y, b1.z, b1.w};
#pragma unroll
    for (int e = 0; e < 8; ++e) out[0][e] = f2bf(bs[e]);
    const float4* sp = (const float4*)(SW + ((size_t)o * IN_F + i0) * 8);
#pragma unroll
    for (int e = 0; e < 8; ++e) {
      float4 s0 = sp[e * 2], s1 = sp[e * 2 + 1];
      out[1][e] = f2bf(s0.x);
      out[2][e] = f2bf(s0.y);
      out[3][e] = f2bf(s0.z);
      out[4][e] = f2bf(s0.w);
      out[5][e] = f2bf(s1.x);
      out[6][e] = f2bf(s1.y);
      out[7][e] = f2bf(s1.z);
      out[8][e] = f2bf(s1.w);
    }
    u16* row = Wa + (size_t)o * KAUG + i0;
#pragma unroll
    for (int c = 0; c < 9; ++c) *(u16x8*)(row + c * IN_F) = out[c];
  }
}

// ---- stage 3: bf16 MFMA GEMM, C = A * B^T, skewed-wave schedule (R9) --------
#define BM 256
#define BN 128
#define BK 64
#define NT (KAUG / BK)          // 144 K-tiles

__device__ __forceinline__ void async16(const u16* g, u16* l) {
  __builtin_amdgcn_global_load_lds(
      (const __attribute__((address_space(1))) u16*)g,
      (__attribute__((address_space(3))) u16*)l,
      16, 0, 0);
}

__global__ __launch_bounds__(512) void gemm_bt(
    const u16* __restrict__ A,   // M x K bf16
    const u16* __restrict__ B,   // N x K bf16 (i.e. B^T operand)
    float* __restrict__ C) {     // M x N fp32
  constexpr int N = OUT_F, K = KAUG;
  // 3 buffers x (A 256x64 + B 128x64) bf16 = 3 x 48 KiB = 144 KiB
  __shared__ __align__(16) u16 sm[3][24576];   // A at 0, B at u16 offset 16384

  const int tid = threadIdx.x;

  // XCD-contiguous tiles: 256 wgs / 8 XCDs; XCD x owns bm in [x*4, x*4+4).
  const int bid = blockIdx.x;
  const int wg  = (bid & 7) * 32 + (bid >> 3);   // bijective (256 = 8*32)
  const int bm  = wg >> 3;                       // 0..31
  const int bn  = wg & 7;                        // 0..7

  const int lane = tid & 63;
  const int wid  = tid >> 6;                     // 8 waves
  const int wm   = wid >> 1;                     // 0..3  (64-row strip)
  const int wn   = wid & 1;                      // 0..1  (64-col strip)
  const int fr   = lane & 15;
  const int hi   = lane >> 4;

  // swizzled k-offsets (u16 units): granule g = (kc<<2)|hi, XOR'd by row&7 (= fr&7)
  const int ak0 = ((hi      ^ (fr & 7)) << 3);
  const int ak1 = (((4 | hi) ^ (fr & 7)) << 3);
  int arow[4], brow[4];
#pragma unroll
  for (int m = 0; m < 4; ++m) arow[m] = (wm * 64 + m * 16 + fr) * 64;
#pragma unroll
  for (int n = 0; n < 4; ++n) brow[n] = 16384 + (wn * 64 + n * 16 + fr) * 64;

  // staging: thread -> LDS row s*64 + tid/8, granule tid&7 (linear dest);
  // inverse-swizzle applied on the GLOBAL source granule (rule #21).
  const int trow = tid >> 3;
  const int gsrc = (tid & 7) ^ (trow & 7);
  const u16* Asrc = A + (size_t)(bm * BM + trow) * K + gsrc * 8;
  const u16* Bsrc = B + (size_t)(bn * BN + trow) * K + gsrc * 8;

  // prologue: stage K-tiles 0 and 1 (6 loads each, in order)
#pragma unroll
  for (int tt = 0; tt < 2; ++tt) {
    u16* dA = &sm[tt][0] + tid * 8;
    u16* dB = &sm[tt][16384] + tid * 8;
    const size_t kg = (size_t)tt * BK;
    async16(Asrc + kg, dA);
    async16(Asrc + (size_t)64  * K + kg, dA + 4096);
    async16(Asrc + (size_t)128 * K + kg, dA + 8192);
    async16(Asrc + (size_t)192 * K + kg, dA + 12288);
    async16(Bsrc + kg, dB);
    async16(Bsrc + (size_t)64  * K + kg, dB + 4096);
  }

  f32x4 acc[4][4] = {};

  for (int t = 0; t < NT; ++t) {
    const int cur = t % 3;
    const int nxt = (t + 2) % 3;
    const bool pf = (t + 2) < NT;
    const size_t kg = (size_t)(t + 2) * BK;
    const u16* s0 = &sm[cur][0];
    u16* dA = &sm[nxt][0] + tid * 8;
    u16* dB = &sm[nxt][16384] + tid * 8;

    // counted wait: leave stage(t+1)'s 6 loads in flight; stage(t) landed.
    if (t < NT - 1) asm volatile("s_waitcnt vmcnt(6)" ::: "memory");
    else            asm volatile("s_waitcnt vmcnt(0)" ::: "memory");
    __builtin_amdgcn_s_barrier();                // ONLY barrier per K-tile:
    // publishes tile t; also proves every wave finished tile t-1 reads, so
    // overwriting buffer (t+2)%3 (last read at t-1) below is race-free.
    __builtin_amdgcn_sched_barrier(0);           // nothing above buffer-valid

    bf16x8 aa[4], bf[4];
    // ---- half-K kc0: reads + 3 stage issues + 16 MFMA (no barrier) ----
#pragma unroll
    for (int n = 0; n < 4; ++n) bf[n] = *(const bf16x8*)(s0 + brow[n] + ak0);
#pragma unroll
    for (int m = 0; m < 4; ++m) aa[m] = *(const bf16x8*)(s0 + arow[m] + ak0);
    if (pf) {
      async16(Asrc + kg, dA);
      async16(Asrc + (size_t)64  * K + kg, dA + 4096);
      async16(Asrc + (size_t)128 * K + kg, dA + 8192);
    }
    __builtin_amdgcn_s_setprio(1);
#pragma unroll
    for (int m = 0; m < 4; ++m)
#pragma unroll
      for (int n = 0; n < 4; ++n)
        acc[m][n] = __builtin_amdgcn_mfma_f32_16x16x32_bf16(aa[m], bf[n], acc[m][n], 0, 0, 0);
    __builtin_amdgcn_s_setprio(0);
    // ---- half-K kc1: reads + 3 stage issues + 16 MFMA (no barrier) ----
#pragma unroll
    for (int n = 0; n < 4; ++n) bf[n] = *(const bf16x8*)(s0 + brow[n] + ak1);
#pragma unroll
    for (int m = 0; m < 4; ++m) aa[m] = *(const bf16x8*)(s0 + arow[m] + ak1);
    if (pf) {
      async16(Asrc + (size_t)192 * K + kg, dA + 12288);
      async16(Bsrc + kg, dB);
      async16(Bsrc + (size_t)64  * K + kg, dB + 4096);
    }
    __builtin_amdgcn_s_setprio(1);
#pragma unroll
    for (int m = 0; m < 4; ++m)
#pragma unroll
      for (int n = 0; n < 4; ++n)
        acc[m][n] = __builtin_amdgcn_mfma_f32_16x16x32_bf16(aa[m], bf[n], acc[m][n], 0, 0, 0);
    __builtin_amdgcn_s_setprio(0);
  }

  // C/D layout (16x16): col = lane&15, row = (lane>>4)*4 + reg
  const int r0 = bm * BM + wm * 64 + hi * 4;
  const int c0 = bn * BN + wn * 64 + fr;
#pragma unroll
  for (int i = 0; i < 4; ++i)
#pragma unroll
    for (int j = 0; j < 4; ++j) {
      float* cp = C + (size_t)(r0 + i * 16) * N + (c0 + j * 16);
#pragma unroll
      for (int r = 0; r < 4; ++r) cp[(size_t)r * N] = acc[i][j][r];
    }
}

extern "C" void kernel_launch(void* const* d_in, const int* in_sizes, int n_in,
                              void* d_out, int out_size, void* d_ws, size_t ws_size,
                              hipStream_t stream) {
  const float* x  = (const float*)d_in[0];   // (8192, 1024)
  const float* bw = (const float*)d_in[1];   // (1024, 1024)
  const float* sw = (const float*)d_in[2];   // (1024, 1024, 8)
  // d_in[3] = grid (1024, 12): compile-time uniform knots; unused.
  float* out = (float*)d_out;                // (8192, 1024)

  u16* Aaug = (u16*)d_ws;                    // 151 MB
  u16* Waug = Aaug + (size_t)BATCH * KAUG;   // 19 MB

  build_AW<<<dim3((BATCH + OUT_F) * 128 / 256), 256, 0, stream>>>(x, bw, sw, Aaug, Waug);
  gemm_bt<<<dim3(BATCH / BM * (OUT_F / BN)), 512, 0, stream>>>(Aaug, Waug, out);
}